// Round 1
// baseline (2748.046 us; speedup 1.0000x reference)
//
#include <hip/hip_runtime.h>
#include <hip/hip_bf16.h>
#include <math.h>

#define B_TOTAL 40960
#define NGRP 20
#define GSZ 2048
#define HPAD 68   // LDS row stride (floats) for transposed activation tiles

// ---------------- group scatter ----------------
__global__ void k_scatter(const int* __restrict__ bid, int* __restrict__ grp,
                          int* __restrict__ cnt)
{
    int i = blockIdx.x * 256 + threadIdx.x;
    if (i < B_TOTAL) {
        int g = bid[i];
        int p = atomicAdd(&cnt[g], 1);
        grp[g * GSZ + p] = i;
    }
}

// ---------------- kNN (per group, K=3) ----------------
__global__ __launch_bounds__(256) void k_knn(const float* __restrict__ x,
                                             const int* __restrict__ grp,
                                             int* __restrict__ nbr)
{
    __shared__ float cb[64][65];   // candidate coords, padded (bank-conflict-free norms)
    __shared__ float cn[64];       // candidate squared norms
    __shared__ int   cix[64];      // candidate global ids
    const int tid = threadIdx.x;
    const int g = blockIdx.y;
    const int qi = grp[g * GSZ + blockIdx.x * 256 + tid];

    float qc[63];
    {
        const float2* xr = (const float2*)(x + (size_t)qi * 90);  // 8B-aligned (90*4*qi % 8 == 0)
        #pragma unroll
        for (int d = 0; d < 31; d++) { float2 v = xr[d]; qc[2*d] = v.x; qc[2*d+1] = v.y; }
        qc[62] = x[(size_t)qi * 90 + 62];
    }
    float qn = 0.f;
    #pragma unroll
    for (int d = 0; d < 63; d++) qn = fmaf(qc[d], qc[d], qn);

    float t0v = 3.4e38f, t1v = 3.4e38f, t2v = 3.4e38f;
    int   t0i = 0, t1i = 0, t2i = 0;

    for (int c0 = 0; c0 < GSZ; c0 += 64) {
        __syncthreads();
        if (tid < 64) cix[tid] = grp[g * GSZ + c0 + tid];
        __syncthreads();
        for (int s = tid; s < 64 * 64; s += 256) {
            int ci = s >> 6, d = s & 63;
            if (d < 63) cb[ci][d] = x[(size_t)cix[ci] * 90 + d];
        }
        __syncthreads();
        if (tid < 64) {
            float a = 0.f;
            #pragma unroll
            for (int d = 0; d < 63; d++) a = fmaf(cb[tid][d], cb[tid][d], a);
            cn[tid] = a;
        }
        __syncthreads();
        for (int ci = 0; ci < 64; ci++) {
            int gj = cix[ci];
            float s0 = 0.f, s1 = 0.f, s2 = 0.f, s3 = 0.f;
            #pragma unroll
            for (int d = 0; d < 60; d += 4) {
                s0 = fmaf(qc[d],   cb[ci][d],   s0);
                s1 = fmaf(qc[d+1], cb[ci][d+1], s1);
                s2 = fmaf(qc[d+2], cb[ci][d+2], s2);
                s3 = fmaf(qc[d+3], cb[ci][d+3], s3);
            }
            s0 = fmaf(qc[60], cb[ci][60], s0);
            s1 = fmaf(qc[61], cb[ci][61], s1);
            s2 = fmaf(qc[62], cb[ci][62], s2);
            float dot = (s0 + s1) + (s2 + s3);
            float d2 = qn + cn[ci] - 2.f * dot;   // same formula as reference
            if (gj != qi) {
                if (d2 < t0v)      { t2v=t1v; t2i=t1i; t1v=t0v; t1i=t0i; t0v=d2; t0i=gj; }
                else if (d2 < t1v) { t2v=t1v; t2i=t1i; t1v=d2;  t1i=gj; }
                else if (d2 < t2v) { t2v=d2;  t2i=gj; }
            }
        }
    }
    nbr[(size_t)qi * 3 + 0] = t0i;
    nbr[(size_t)qi * 3 + 1] = t1i;
    nbr[(size_t)qi * 3 + 2] = t2i;
}

// ---------------- fused trunk MLP ----------------
// hT layout: rows 0..255 = h (transposed), rows 256..318 = xyz (transposed)
template<int MODE>   // 0: K rows from h; 1: K rows from xyz; 2: skip (xyz then h)
__device__ __forceinline__ void trunk_layer(float (*hT)[HPAD], float (*wbuf)[256],
        const float* __restrict__ W, const float* __restrict__ bias,
        int K, int do_relu, float* __restrict__ gout, int row0)
{
    const int tid = threadIdx.x;
    const int tx = tid & 31, ty = tid >> 5;
    const int c0 = tx * 8, r0 = ty * 8;
    float acc[8][8];
    #pragma unroll
    for (int i = 0; i < 8; i++)
        #pragma unroll
        for (int j = 0; j < 8; j++) acc[i][j] = 0.f;

    for (int k0 = 0; k0 < K; k0 += 32) {
        const int kc = (K - k0 < 32) ? (K - k0) : 32;
        __syncthreads();
        for (int s = tid; s < (kc << 8); s += 256) {
            int kk = s >> 8, c = s & 255;
            wbuf[kk][c] = W[(size_t)(k0 + kk) * 256 + c];
        }
        __syncthreads();
        for (int kk = 0; kk < kc; kk++) {
            const int k = k0 + kk;
            int lr;
            if (MODE == 0) lr = k;
            else if (MODE == 1) lr = 256 + k;
            else lr = (k < 63) ? (256 + k) : (k - 63);
            float4 a0 = *(const float4*)&hT[lr][r0];
            float4 a1 = *(const float4*)&hT[lr][r0 + 4];
            float4 w0v = *(const float4*)&wbuf[kk][c0];
            float4 w1v = *(const float4*)&wbuf[kk][c0 + 4];
            float av[8] = {a0.x,a0.y,a0.z,a0.w,a1.x,a1.y,a1.z,a1.w};
            float bv[8] = {w0v.x,w0v.y,w0v.z,w0v.w,w1v.x,w1v.y,w1v.z,w1v.w};
            #pragma unroll
            for (int i = 0; i < 8; i++)
                #pragma unroll
                for (int j = 0; j < 8; j++)
                    acc[i][j] = fmaf(av[i], bv[j], acc[i][j]);
        }
    }
    float bb[8];
    #pragma unroll
    for (int j = 0; j < 8; j++) bb[j] = bias[c0 + j];
    #pragma unroll
    for (int i = 0; i < 8; i++)
        #pragma unroll
        for (int j = 0; j < 8; j++) {
            float v = acc[i][j] + bb[j];
            acc[i][j] = do_relu ? fmaxf(v, 0.f) : v;
        }
    __syncthreads();   // all reads of old hT complete before overwrite
    if (gout) {
        #pragma unroll
        for (int i = 0; i < 8; i++) {
            float4 lo = make_float4(acc[i][0], acc[i][1], acc[i][2], acc[i][3]);
            float4 hi = make_float4(acc[i][4], acc[i][5], acc[i][6], acc[i][7]);
            *(float4*)&gout[(size_t)(row0 + r0 + i) * 256 + c0]     = lo;
            *(float4*)&gout[(size_t)(row0 + r0 + i) * 256 + c0 + 4] = hi;
        }
    } else {
        #pragma unroll
        for (int j = 0; j < 8; j++) {
            float4 lo = make_float4(acc[0][j], acc[1][j], acc[2][j], acc[3][j]);
            float4 hi = make_float4(acc[4][j], acc[5][j], acc[6][j], acc[7][j]);
            *(float4*)&hT[c0 + j][r0]     = lo;
            *(float4*)&hT[c0 + j][r0 + 4] = hi;
        }
    }
}

__global__ __launch_bounds__(256) void k_trunk(const float* __restrict__ x,
    const float* __restrict__ w0, const float* __restrict__ b0,
    const float* __restrict__ wmid, const float* __restrict__ bmid,
    const float* __restrict__ wskip, const float* __restrict__ bskip,
    const float* __restrict__ wfin, const float* __restrict__ bfin,
    const float* __restrict__ wsig, const float* __restrict__ bsig,
    float* __restrict__ feat, float* __restrict__ out)
{
    __shared__ float hT[319][HPAD];
    __shared__ float wbuf[32][256];
    const int tid = threadIdx.x;
    const int row0 = blockIdx.x * 64;
    for (int s = tid; s < 63 * 64; s += 256) {
        int k = s >> 6, r = s & 63;
        hT[256 + k][r] = x[(size_t)(row0 + r) * 90 + k];
    }
    trunk_layer<1>(hT, wbuf, w0, b0, 63, 1, nullptr, row0);
    trunk_layer<0>(hT, wbuf, wmid + 0*65536, bmid + 0*256, 256, 1, nullptr, row0);
    trunk_layer<0>(hT, wbuf, wmid + 1*65536, bmid + 1*256, 256, 1, nullptr, row0);
    trunk_layer<0>(hT, wbuf, wmid + 2*65536, bmid + 2*256, 256, 1, nullptr, row0);
    trunk_layer<2>(hT, wbuf, wskip, bskip, 319, 1, nullptr, row0);
    trunk_layer<0>(hT, wbuf, wmid + 3*65536, bmid + 3*256, 256, 1, nullptr, row0);
    trunk_layer<0>(hT, wbuf, wmid + 4*65536, bmid + 4*256, 256, 1, nullptr, row0);
    trunk_layer<0>(hT, wbuf, wmid + 5*65536, bmid + 5*256, 256, 1, nullptr, row0);
    trunk_layer<0>(hT, wbuf, wfin, bfin, 256, 0, feat, row0);   // feat, no relu
    __syncthreads();
    if (tid < 64) {   // sigma from final h (still in hT)
        float s = bsig[0];
        for (int k = 0; k < 256; k++) s = fmaf(hT[k][tid], wsig[k], s);
        out[(size_t)(row0 + tid) * 4 + 3] = s;
    }
}

// ---------------- PQ GEMMs for edge convs ----------------
// PQ1: Xe=[feat(256), dir(27)] (K=283); cols 0..127 = Xe@W_top, 128..255 = Xe@W_bot
__global__ __launch_bounds__(256) void k_pq1(const float* __restrict__ feat,
    const float* __restrict__ x, const float* __restrict__ ew1,
    float* __restrict__ PQ)
{
    __shared__ float aT[283][HPAD];
    __shared__ float wbuf[32][256];
    const int tid = threadIdx.x;
    const int tx = tid & 31, ty = tid >> 5;
    const int c0 = tx * 8, r0 = ty * 8;
    const int row0 = blockIdx.x * 64;
    for (int s = tid; s < 64 * 256; s += 256) {
        int r = s >> 8, k = s & 255;
        aT[k][r] = feat[(size_t)(row0 + r) * 256 + k];
    }
    for (int s = tid; s < 27 * 64; s += 256) {
        int dd = s >> 6, r = s & 63;
        aT[256 + dd][r] = x[(size_t)(row0 + r) * 90 + 63 + dd];
    }
    float acc[8][8];
    #pragma unroll
    for (int i = 0; i < 8; i++)
        #pragma unroll
        for (int j = 0; j < 8; j++) acc[i][j] = 0.f;
    for (int k0 = 0; k0 < 283; k0 += 32) {
        const int kc = (283 - k0 < 32) ? (283 - k0) : 32;
        __syncthreads();
        for (int s = tid; s < (kc << 8); s += 256) {
            int kk = s >> 8, c = s & 255;
            int k = k0 + kk;
            wbuf[kk][c] = (c < 128) ? ew1[(size_t)k * 128 + c]
                                    : ew1[(size_t)(283 + k) * 128 + (c - 128)];
        }
        __syncthreads();
        for (int kk = 0; kk < kc; kk++) {
            const int k = k0 + kk;
            float4 a0 = *(const float4*)&aT[k][r0];
            float4 a1 = *(const float4*)&aT[k][r0 + 4];
            float4 w0v = *(const float4*)&wbuf[kk][c0];
            float4 w1v = *(const float4*)&wbuf[kk][c0 + 4];
            float av[8] = {a0.x,a0.y,a0.z,a0.w,a1.x,a1.y,a1.z,a1.w};
            float bv[8] = {w0v.x,w0v.y,w0v.z,w0v.w,w1v.x,w1v.y,w1v.z,w1v.w};
            #pragma unroll
            for (int i = 0; i < 8; i++)
                #pragma unroll
                for (int j = 0; j < 8; j++)
                    acc[i][j] = fmaf(av[i], bv[j], acc[i][j]);
        }
    }
    #pragma unroll
    for (int i = 0; i < 8; i++) {
        float4 lo = make_float4(acc[i][0], acc[i][1], acc[i][2], acc[i][3]);
        float4 hi = make_float4(acc[i][4], acc[i][5], acc[i][6], acc[i][7]);
        *(float4*)&PQ[(size_t)(row0 + r0 + i) * 256 + c0]     = lo;
        *(float4*)&PQ[(size_t)(row0 + r0 + i) * 256 + c0 + 4] = hi;
    }
}

// PQ2: input d1 (K=128)
__global__ __launch_bounds__(256) void k_pq2(const float* __restrict__ d1,
    const float* __restrict__ ew1, float* __restrict__ PQ)
{
    __shared__ float aT[128][HPAD];
    __shared__ float wbuf[32][256];
    const int tid = threadIdx.x;
    const int tx = tid & 31, ty = tid >> 5;
    const int c0 = tx * 8, r0 = ty * 8;
    const int row0 = blockIdx.x * 64;
    for (int s = tid; s < 64 * 128; s += 256) {
        int r = s >> 7, k = s & 127;
        aT[k][r] = d1[(size_t)(row0 + r) * 128 + k];
    }
    float acc[8][8];
    #pragma unroll
    for (int i = 0; i < 8; i++)
        #pragma unroll
        for (int j = 0; j < 8; j++) acc[i][j] = 0.f;
    for (int k0 = 0; k0 < 128; k0 += 32) {
        __syncthreads();
        for (int s = tid; s < 32 * 256; s += 256) {
            int kk = s >> 8, c = s & 255;
            int k = k0 + kk;
            wbuf[kk][c] = (c < 128) ? ew1[(size_t)k * 128 + c]
                                    : ew1[(size_t)(128 + k) * 128 + (c - 128)];
        }
        __syncthreads();
        for (int kk = 0; kk < 32; kk++) {
            const int k = k0 + kk;
            float4 a0 = *(const float4*)&aT[k][r0];
            float4 a1 = *(const float4*)&aT[k][r0 + 4];
            float4 w0v = *(const float4*)&wbuf[kk][c0];
            float4 w1v = *(const float4*)&wbuf[kk][c0 + 4];
            float av[8] = {a0.x,a0.y,a0.z,a0.w,a1.x,a1.y,a1.z,a1.w};
            float bv[8] = {w0v.x,w0v.y,w0v.z,w0v.w,w1v.x,w1v.y,w1v.z,w1v.w};
            #pragma unroll
            for (int i = 0; i < 8; i++)
                #pragma unroll
                for (int j = 0; j < 8; j++)
                    acc[i][j] = fmaf(av[i], bv[j], acc[i][j]);
        }
    }
    #pragma unroll
    for (int i = 0; i < 8; i++) {
        float4 lo = make_float4(acc[i][0], acc[i][1], acc[i][2], acc[i][3]);
        float4 hi = make_float4(acc[i][4], acc[i][5], acc[i][6], acc[i][7]);
        *(float4*)&PQ[(size_t)(row0 + r0 + i) * 256 + c0]     = lo;
        *(float4*)&PQ[(size_t)(row0 + r0 + i) * 256 + c0 + 4] = hi;
    }
}

// ---------------- edge conv (h1 = relu(P_i + Q_j - Q_i + b1); h2 = relu(h1@w2+b2); mean) ----------------
template<int RGB>
__global__ __launch_bounds__(256) void k_edge(const float* __restrict__ PQ,
    const float* __restrict__ b1, const float* __restrict__ w2,
    const float* __restrict__ b2, const int* __restrict__ nbr,
    float* __restrict__ dout,
    const float* __restrict__ wrgb, const float* __restrict__ brgb,
    float* __restrict__ out)
{
    __shared__ float h1T[128][97];   // [col][edge], stride 97 => conflict-free
    __shared__ float wb[32][128];
    const int tid = threadIdx.x;
    const int n0 = blockIdx.x * 32;
    {
        const int c = tid & 127, eg = tid >> 7;
        const float bias = b1[c];
        for (int e = eg; e < 96; e += 2) {
            int n = e / 3;
            int jj = e - n * 3;
            int i = n0 + n;
            int j = nbr[(size_t)i * 3 + jj];
            float v = PQ[(size_t)i * 256 + c] + bias
                    + PQ[(size_t)j * 256 + 128 + c] - PQ[(size_t)i * 256 + 128 + c];
            h1T[c][e] = fmaxf(v, 0.f);
        }
    }
    const int cg = tid & 15, rg = tid >> 4;
    const int c0 = cg * 8, e0 = rg * 6;
    float acc[6][8];
    #pragma unroll
    for (int m = 0; m < 6; m++)
        #pragma unroll
        for (int j = 0; j < 8; j++) acc[m][j] = 0.f;
    for (int k0 = 0; k0 < 128; k0 += 32) {
        __syncthreads();
        for (int s = tid; s < 32 * 128; s += 256) {
            int kk = s >> 7, c = s & 127;
            wb[kk][c] = w2[(size_t)(k0 + kk) * 128 + c];
        }
        __syncthreads();
        for (int kk = 0; kk < 32; kk++) {
            const int k = k0 + kk;
            float av[6];
            #pragma unroll
            for (int m = 0; m < 6; m++) av[m] = h1T[k][e0 + m];
            float4 w0v = *(const float4*)&wb[kk][c0];
            float4 w1v = *(const float4*)&wb[kk][c0 + 4];
            float bv[8] = {w0v.x,w0v.y,w0v.z,w0v.w,w1v.x,w1v.y,w1v.z,w1v.w};
            #pragma unroll
            for (int m = 0; m < 6; m++)
                #pragma unroll
                for (int j = 0; j < 8; j++)
                    acc[m][j] = fmaf(av[m], bv[j], acc[m][j]);
        }
    }
    float bb[8];
    #pragma unroll
    for (int j = 0; j < 8; j++) bb[j] = b2[c0 + j];
    float dA[8], dB[8];
    #pragma unroll
    for (int j = 0; j < 8; j++) {
        float h0 = fmaxf(acc[0][j] + bb[j], 0.f);
        float h1 = fmaxf(acc[1][j] + bb[j], 0.f);
        float h2 = fmaxf(acc[2][j] + bb[j], 0.f);
        float h3 = fmaxf(acc[3][j] + bb[j], 0.f);
        float h4 = fmaxf(acc[4][j] + bb[j], 0.f);
        float h5 = fmaxf(acc[5][j] + bb[j], 0.f);
        dA[j] = (h0 + h1 + h2) * (1.f / 3.f);
        dB[j] = (h3 + h4 + h5) * (1.f / 3.f);
    }
    if (!RGB) {
        float4 lo, hi;
        lo = make_float4(dA[0], dA[1], dA[2], dA[3]);
        hi = make_float4(dA[4], dA[5], dA[6], dA[7]);
        *(float4*)&dout[(size_t)(n0 + 2*rg) * 128 + c0]     = lo;
        *(float4*)&dout[(size_t)(n0 + 2*rg) * 128 + c0 + 4] = hi;
        lo = make_float4(dB[0], dB[1], dB[2], dB[3]);
        hi = make_float4(dB[4], dB[5], dB[6], dB[7]);
        *(float4*)&dout[(size_t)(n0 + 2*rg + 1) * 128 + c0]     = lo;
        *(float4*)&dout[(size_t)(n0 + 2*rg + 1) * 128 + c0 + 4] = hi;
    } else {
        __syncthreads();                 // done reading h1T; reuse as d2 tile
        float* d2L = &h1T[0][0];         // [32][130]
        #pragma unroll
        for (int j = 0; j < 8; j++) {
            d2L[(2*rg)     * 130 + c0 + j] = dA[j];
            d2L[(2*rg + 1) * 130 + c0 + j] = dB[j];
        }
        __syncthreads();
        if (tid < 96) {
            int n = tid / 3, ch = tid - 3 * (tid / 3);
            float s = brgb[ch];
            for (int k = 0; k < 128; k++) s = fmaf(d2L[n * 130 + k], wrgb[k * 3 + ch], s);
            out[(size_t)(n0 + n) * 4 + ch] = 1.f / (1.f + expf(-s));
        }
    }
}

// ---------------- launch ----------------
extern "C" void kernel_launch(void* const* d_in, const int* in_sizes, int n_in,
                              void* d_out, int out_size, void* d_ws, size_t ws_size,
                              hipStream_t stream)
{
    const float* x     = (const float*)d_in[0];
    const int*   bid   = (const int*)d_in[1];
    const float* w0    = (const float*)d_in[2];
    const float* b0    = (const float*)d_in[3];
    const float* wmid  = (const float*)d_in[4];
    const float* bmid  = (const float*)d_in[5];
    const float* wskip = (const float*)d_in[6];
    const float* bskip = (const float*)d_in[7];
    const float* wfin  = (const float*)d_in[8];
    const float* bfin  = (const float*)d_in[9];
    const float* wsig  = (const float*)d_in[10];
    const float* bsig  = (const float*)d_in[11];
    const float* e1w1  = (const float*)d_in[12];
    const float* e1b1  = (const float*)d_in[13];
    const float* e1w2  = (const float*)d_in[14];
    const float* e1b2  = (const float*)d_in[15];
    const float* e2w1  = (const float*)d_in[16];
    const float* e2b1  = (const float*)d_in[17];
    const float* e2w2  = (const float*)d_in[18];
    const float* e2b2  = (const float*)d_in[19];
    const float* wrgb  = (const float*)d_in[20];
    const float* brgb  = (const float*)d_in[21];
    float* out = (float*)d_out;

    char* ws = (char*)d_ws;
    int* cnt = (int*)ws;                                   // 20 ints
    int* grp = (int*)(ws + 256);                           // 20*2048 ints
    int* nbr = (int*)(ws + 256 + NGRP * GSZ * 4);          // 40960*3 ints
    float* bufA = (float*)(ws + (1 << 20));                // 40960*256 f32 (feat, later d1)
    float* bufB = bufA + (size_t)B_TOTAL * 256;            // 40960*256 f32 (PQ1, later PQ2)

    hipMemsetAsync(cnt, 0, 256, stream);
    k_scatter<<<B_TOTAL / 256, 256, 0, stream>>>(bid, grp, cnt);
    k_knn<<<dim3(GSZ / 256, NGRP), 256, 0, stream>>>(x, grp, nbr);
    k_trunk<<<B_TOTAL / 64, 256, 0, stream>>>(x, w0, b0, wmid, bmid, wskip, bskip,
                                              wfin, bfin, wsig, bsig, bufA, out);
    k_pq1<<<B_TOTAL / 64, 256, 0, stream>>>(bufA, x, e1w1, bufB);
    k_edge<0><<<B_TOTAL / 32, 256, 0, stream>>>(bufB, e1b1, e1w2, e1b2, nbr, bufA,
                                                nullptr, nullptr, nullptr);
    k_pq2<<<B_TOTAL / 64, 256, 0, stream>>>(bufA, e2w1, bufB);
    k_edge<1><<<B_TOTAL / 32, 256, 0, stream>>>(bufB, e2b1, e2w2, e2b2, nbr, nullptr,
                                                wrgb, brgb, out);
}